// Round 3
// baseline (7634.261 us; speedup 1.0000x reference)
//
#include <hip/hip_runtime.h>
#include <hip/hip_cooperative_groups.h>
#include <math.h>

namespace cg = cooperative_groups;

// DNC forward, cooperative: 32 blocks, 4 grid-synced phases per step.
// P1/P2/P3: weight-column-sliced across blocks (each weight byte read by ONE
// block -> slices L2-resident). P4: memory module batch-parallel (M/L in LDS).

#define TT   64
#define BB   32
#define INW  64
#define OUTW 64
#define NN   128
#define WD   64
#define RR   4
#define HH   256
#define IFSZ 471
#define CLIPV 20.0f
#define EPSV  1e-6f

// interface vector offsets
#define OFF_RK   0
#define OFF_RSTR 256
#define OFF_WK   260
#define OFF_WSTR 324
#define OFF_ER   325
#define OFF_WV   389
#define OFF_FG   453
#define OFF_AG   457
#define OFF_WG   458
#define OFF_MD   459

// scal[] slots
#define S_WSTR 0
#define S_AG   1
#define S_WG   2
#define S_KNW  3
#define S_WSUM 4
#define S_RSTR 8
#define S_FG   12
#define S_KNR  16
#define S_BM   20
#define S_FM   24
#define S_CM   28

// LDS layout (floats)
#define L_MS   0        // [128][65]
#define L_LS   8320     // [128][129]
#define L_C0   24832    // [32][8] c0 slice
#define L_C1   25088    // [32][8] c1 slice
#define L_WW   25344    // 128
#define L_PRC  25472    // 128
#define L_USG  25600    // 128
#define L_RWS  25728    // 512
#define L_WC   26240    // [128][36] weight chunk (cap 4608)
#define L_XC   30848    // [128][36] X chunk (transposed, cap 4608)
#define L_GL   35456    // 1024 gate scratch
#define SMEM_FLOATS 36480
#define SMEM_BYTES  (SMEM_FLOATS*4)

// P4 overlays (inside [L_WC, L_GL) region, time-disjoint with P1-P3 scratch)
#define L_IFC  26240   // 472
#define L_CTL  26712   // 256
#define L_RDS  26968   // 256
#define L_FWD  27224   // 512
#define L_BWD  27736   // 512
#define L_U2   28248   // 128
#define L_WCS  28376   // 128
#define L_RCS  28504   // 512
#define L_MNO  29016   // 128
#define L_ERS  29144   // 64
#define L_WVS  29208   // 64
#define L_SC   29272   // 64
#define L_SCAL 29336   // 32
#define L_PART 29368   // 1024

// global workspace layout (floats)
#define W_H0   0       // [2][32*256] ping-pong
#define W_H1   16384   // [2][32*256] ping-pong
#define W_CTL  32768   // [32*256]
#define W_RDS  40960   // [32*256]
#define W_IFC  49152   // [32*471]
#define W_TOTAL 64224

__device__ __forceinline__ float sigf(float x){ return 1.0f/(1.0f+expf(-x)); }
__device__ __forceinline__ float sofp(float x){ return fmaxf(x,0.0f)+log1pf(expf(-fabsf(x))); }

__device__ __forceinline__ float wredSum(float v){
  #pragma unroll
  for (int m=32;m>0;m>>=1) v += __shfl_xor(v,m,64);
  return v;
}
__device__ __forceinline__ float wredMax(float v){
  #pragma unroll
  for (int m=32;m>0;m>>=1) v = fmaxf(v,__shfl_xor(v,m,64));
  return v;
}

extern "C" __global__ __launch_bounds__(1024, 1)
void dnc_coop(const float* __restrict__ inputs,
              const float* __restrict__ Wx0, const float* __restrict__ Wh0, const float* __restrict__ b0g,
              const float* __restrict__ Wx1, const float* __restrict__ Wh1, const float* __restrict__ b1g,
              const float* __restrict__ Wifg, const float* __restrict__ bifg,
              const float* __restrict__ Woutg, const float* __restrict__ boutg,
              float* __restrict__ outg, float* __restrict__ ws)
{
  cg::grid_group grid = cg::this_grid();
  const int b    = blockIdx.x;
  const int tid  = threadIdx.x;
  const int lane = tid & 63;
  const int wid  = tid >> 6;

  extern __shared__ float sm[];
  float* Ms   = sm + L_MS;
  float* Ls   = sm + L_LS;
  float* c0sl = sm + L_C0;
  float* c1sl = sm + L_C1;
  float* wws  = sm + L_WW;
  float* prc  = sm + L_PRC;
  float* usg  = sm + L_USG;
  float* rws  = sm + L_RWS;
  float* Wc   = sm + L_WC;
  float* Xc   = sm + L_XC;
  float* Gl   = sm + L_GL;
  float* ifcl = sm + L_IFC;
  float* ctll = sm + L_CTL;
  float* rds  = sm + L_RDS;
  float* fwds = sm + L_FWD;
  float* bwds = sm + L_BWD;
  float* u2   = sm + L_U2;
  float* wcs  = sm + L_WCS;
  float* rcs  = sm + L_RCS;
  float* mno  = sm + L_MNO;
  float* ers  = sm + L_ERS;
  float* wvs  = sm + L_WVS;
  float* sc   = sm + L_SC;
  float* scal = sm + L_SCAL;
  float* part = sm + L_PART;

  // ---- init state ----
  for (int i=tid;i<NN*65;i+=1024)  Ms[i]=0.f;
  for (int i=tid;i<NN*129;i+=1024) Ls[i]=0.f;
  if (tid<256){ c0sl[tid]=0.f; c1sl[tid]=0.f; }
  if (tid<128){ wws[tid]=0.f; prc[tid]=0.f; usg[tid]=0.f; }
  if (tid<512) rws[tid]=0.f;
  for (int i=b*1024+tid; i<W_TOTAL; i+=BB*1024) ws[i]=0.f;
  __syncthreads();
  grid.sync();

  const int b2s = tid>>5;     // staging batch row
  const int ks  = tid&15;     // k-slice id within tile group

  for (int t=0;t<TT;++t){
    float* h0old = ws + W_H0 + (t&1)*8192;
    float* h0new = ws + W_H0 + ((t+1)&1)*8192;
    float* h1old = ws + W_H1 + (t&1)*8192;
    float* h1new = ws + W_H1 + ((t+1)&1)*8192;
    float* gctl  = ws + W_CTL;
    float* greads= ws + W_RDS;
    float* gifc  = ws + W_IFC;

    // ================= P1: LSTM0 gates (column-sliced) =================
    {
      float acc[64];
      #pragma unroll
      for (int j=0;j<64;j++) acc[j]=0.f;
      for (int ch=0; ch<6; ++ch){
        const int k0 = ch*96;
        #pragma unroll
        for (int i=0;i<3;i++){                 // stage W chunk [96][32]
          int el = tid + i*1024, r = el>>5, c = el&31;
          int row = k0 + r;
          int col = b*8 + (c&7) + ((c>>3)<<8);
          Wc[r*36+c] = (row<320)? Wx0[row*1024+col] : Wh0[(row-320)*1024+col];
        }
        #pragma unroll
        for (int i=0;i<3;i++){                 // stage X chunk transposed [96][32]
          int kk = (tid&31) + 32*i, kg = k0+kk;
          float v;
          if (kg < 64)       v = inputs[(t*BB + b2s)*INW + kg];
          else if (kg < 320) v = greads[b2s*256 + kg-64];
          else               v = h0old[b2s*256 + kg-320];
          Xc[kk*36 + b2s] = v;
        }
        __syncthreads();
        if (tid < 256){
          const int tile = tid>>4;
          const int B0 = (tile>>2)*8, C0 = (tile&3)*8;
          #pragma unroll
          for (int i=0;i<6;i++){
            int kk = ks + 16*i;
            const float* xp = Xc + kk*36 + B0;
            const float* wp = Wc + kk*36 + C0;
            float4 x0 = *(const float4*)xp, x1 = *(const float4*)(xp+4);
            float4 w0 = *(const float4*)wp, w1 = *(const float4*)(wp+4);
            float xv[8] = {x0.x,x0.y,x0.z,x0.w,x1.x,x1.y,x1.z,x1.w};
            float wv[8] = {w0.x,w0.y,w0.z,w0.w,w1.x,w1.y,w1.z,w1.w};
            #pragma unroll
            for (int ii=0;ii<8;ii++)
              #pragma unroll
              for (int jj=0;jj<8;jj++)
                acc[ii*8+jj] += xv[ii]*wv[jj];
          }
        }
        __syncthreads();
      }
      if (tid < 256){
        const int tile = tid>>4;
        const int B0 = (tile>>2)*8, C0 = (tile&3)*8;
        // reduce-scatter over 16 k-slices (static indexing only)
        #pragma unroll
        for (int st=0; st<4; ++st){
          const int m = 1<<st, half = 32>>st;
          bool hi = (ks & m) != 0;
          #pragma unroll
          for (int j=0;j<half;j++){
            float a = acc[j], bb = acc[j+half];
            float keep = hi? bb : a;
            float send = hi? a : bb;
            acc[j] = keep + __shfl_xor(send, m, 64);
          }
        }
        const int jbase = ((ks&1)?32:0)+((ks&2)?16:0)+((ks&4)?8:0)+((ks&8)?4:0);
        #pragma unroll
        for (int q=0;q<4;q++){
          int j = jbase + q;
          Gl[(B0+(j>>3))*32 + C0 + (j&7)] = acc[q];
        }
      }
      __syncthreads();
      if (tid < 256){
        int b2 = tid>>3, jj = tid&7, base = b2*32, cb = b*8+jj;
        float gi = Gl[base+jj]    + b0g[cb];
        float gf = Gl[base+8+jj]  + b0g[cb+256];
        float gg = Gl[base+16+jj] + b0g[cb+512];
        float go = Gl[base+24+jj] + b0g[cb+768];
        float c = sigf(gf)*c0sl[tid] + sigf(gi)*tanhf(gg);
        c0sl[tid]=c;
        h0new[b2*256 + b*8 + jj] = sigf(go)*tanhf(c);
      }
    }
    grid.sync();

    // ================= P2: LSTM1 gates (column-sliced) =================
    {
      float acc[64];
      #pragma unroll
      for (int j=0;j<64;j++) acc[j]=0.f;
      for (int ch=0; ch<4; ++ch){
        const int k0 = ch*128;
        #pragma unroll
        for (int i=0;i<4;i++){                 // stage W chunk [128][32]
          int el = tid + i*1024, r = el>>5, c = el&31;
          int row = k0 + r;
          int col = b*8 + (c&7) + ((c>>3)<<8);
          Wc[r*36+c] = (row<256)? Wx1[row*1024+col] : Wh1[(row-256)*1024+col];
        }
        #pragma unroll
        for (int i=0;i<4;i++){                 // stage X chunk
          int kk = (tid&31) + 32*i, kg = k0+kk;
          float v = (kg<256)? h0new[b2s*256+kg] : h1old[b2s*256+kg-256];
          Xc[kk*36 + b2s] = v;
        }
        __syncthreads();
        if (tid < 256){
          const int tile = tid>>4;
          const int B0 = (tile>>2)*8, C0 = (tile&3)*8;
          #pragma unroll
          for (int i=0;i<8;i++){
            int kk = ks + 16*i;
            const float* xp = Xc + kk*36 + B0;
            const float* wp = Wc + kk*36 + C0;
            float4 x0 = *(const float4*)xp, x1 = *(const float4*)(xp+4);
            float4 w0 = *(const float4*)wp, w1 = *(const float4*)(wp+4);
            float xv[8] = {x0.x,x0.y,x0.z,x0.w,x1.x,x1.y,x1.z,x1.w};
            float wv[8] = {w0.x,w0.y,w0.z,w0.w,w1.x,w1.y,w1.z,w1.w};
            #pragma unroll
            for (int ii=0;ii<8;ii++)
              #pragma unroll
              for (int jj=0;jj<8;jj++)
                acc[ii*8+jj] += xv[ii]*wv[jj];
          }
        }
        __syncthreads();
      }
      if (tid < 256){
        const int tile = tid>>4;
        const int B0 = (tile>>2)*8, C0 = (tile&3)*8;
        #pragma unroll
        for (int st=0; st<4; ++st){
          const int m = 1<<st, half = 32>>st;
          bool hi = (ks & m) != 0;
          #pragma unroll
          for (int j=0;j<half;j++){
            float a = acc[j], bb = acc[j+half];
            float keep = hi? bb : a;
            float send = hi? a : bb;
            acc[j] = keep + __shfl_xor(send, m, 64);
          }
        }
        const int jbase = ((ks&1)?32:0)+((ks&2)?16:0)+((ks&4)?8:0)+((ks&8)?4:0);
        #pragma unroll
        for (int q=0;q<4;q++){
          int j = jbase + q;
          Gl[(B0+(j>>3))*32 + C0 + (j&7)] = acc[q];
        }
      }
      __syncthreads();
      if (tid < 256){
        int b2 = tid>>3, jj = tid&7, base = b2*32, cb = b*8+jj;
        float gi = Gl[base+jj]    + b1g[cb];
        float gf = Gl[base+8+jj]  + b1g[cb+256];
        float gg = Gl[base+16+jj] + b1g[cb+512];
        float go = Gl[base+24+jj] + b1g[cb+768];
        float c = sigf(gf)*c1sl[tid] + sigf(gi)*tanhf(gg);
        c1sl[tid]=c;
        float h = sigf(go)*tanhf(c);
        h1new[b2*256 + b*8 + jj] = h;
        gctl[b2*256 + b*8 + jj]  = fminf(CLIPV, fmaxf(-CLIPV, h));
      }
    }
    grid.sync();

    // ================= P3: interface vector (column-sliced) =================
    {
      float acc[64];
      #pragma unroll
      for (int j=0;j<64;j++) acc[j]=0.f;
      const int c0i = b*15;
      const int ncols = (b<31)? 15 : 6;
      for (int ch=0; ch<2; ++ch){
        const int k0 = ch*128;
        #pragma unroll
        for (int i=0;i<2;i++){                 // stage W chunk [128][16]
          int el = tid + i*1024, k = el>>4, c = el&15;
          int col = c0i + c; if (col > 470) col = 470;
          Wc[k*36+c] = Wifg[(k0+k)*IFSZ + col];
        }
        #pragma unroll
        for (int i=0;i<4;i++){
          int kk = (tid&31) + 32*i;
          Xc[kk*36 + b2s] = gctl[b2s*256 + k0+kk];
        }
        __syncthreads();
        if (tid < 128){
          const int B0 = (tid>>5)*8;          // b2 group
          const int C0 = ((tid>>4)&1)*8;      // col group
          #pragma unroll
          for (int i=0;i<8;i++){
            int kk = ks + 16*i;
            const float* xp = Xc + kk*36 + B0;
            const float* wp = Wc + kk*36 + C0;
            float4 x0 = *(const float4*)xp, x1 = *(const float4*)(xp+4);
            float4 w0 = *(const float4*)wp, w1 = *(const float4*)(wp+4);
            float xv[8] = {x0.x,x0.y,x0.z,x0.w,x1.x,x1.y,x1.z,x1.w};
            float wv[8] = {w0.x,w0.y,w0.z,w0.w,w1.x,w1.y,w1.z,w1.w};
            #pragma unroll
            for (int ii=0;ii<8;ii++)
              #pragma unroll
              for (int jj=0;jj<8;jj++)
                acc[ii*8+jj] += xv[ii]*wv[jj];
          }
        }
        __syncthreads();
      }
      if (tid < 128){
        const int B0 = (tid>>5)*8;
        const int C0 = ((tid>>4)&1)*8;
        #pragma unroll
        for (int st=0; st<4; ++st){
          const int m = 1<<st, half = 32>>st;
          bool hi = (ks & m) != 0;
          #pragma unroll
          for (int j=0;j<half;j++){
            float a = acc[j], bb = acc[j+half];
            float keep = hi? bb : a;
            float send = hi? a : bb;
            acc[j] = keep + __shfl_xor(send, m, 64);
          }
        }
        const int jbase = ((ks&1)?32:0)+((ks&2)?16:0)+((ks&4)?8:0)+((ks&8)?4:0);
        #pragma unroll
        for (int q=0;q<4;q++){
          int j = jbase + q, ii = j>>3, jj = j&7;
          int cc = C0 + jj;
          if (cc < ncols)
            gifc[(B0+ii)*IFSZ + c0i + cc] = acc[q] + bifg[c0i+cc];
        }
      }
    }
    grid.sync();

    // ================= P4: memory module (batch-parallel, block b = batch b) =====
    {
      if (tid < IFSZ)               ifcl[tid]     = gifc[b*IFSZ + tid];
      if (tid >= 512 && tid < 768)  ctll[tid-512] = gctl[b*256 + (tid-512)];
      __syncthreads();
      // F: derived scalars + mnorm(old M) + key norms
      if (tid < RR){
        scal[S_RSTR+tid]=1.0f+sofp(ifcl[OFF_RSTR+tid]);
        scal[S_FG+tid]  =sigf(ifcl[OFF_FG+tid]);
        float m0=ifcl[OFF_MD+tid*3], m1=ifcl[OFF_MD+tid*3+1], m2=ifcl[OFF_MD+tid*3+2];
        float mx=fmaxf(m0,fmaxf(m1,m2));
        float e0=expf(m0-mx), e1=expf(m1-mx), e2=expf(m2-mx);
        float s=e0+e1+e2;
        scal[S_BM+tid]=e0/s; scal[S_FM+tid]=e1/s; scal[S_CM+tid]=e2/s;
      }
      if (tid == 4) scal[S_WSTR]=1.0f+sofp(ifcl[OFF_WSTR]);
      if (tid == 5) scal[S_AG]=sigf(ifcl[OFF_AG]);
      if (tid == 6) scal[S_WG]=sigf(ifcl[OFF_WG]);
      if (tid >= 64 && tid < 128){
        int d=tid-64;
        ers[d]=sigf(ifcl[OFF_ER+d]);
        wvs[d]=ifcl[OFF_WV+d];
      }
      if (tid >= 128 && tid < 256){
        int n=tid-128; float s=0.f;
        #pragma unroll 8
        for (int d=0;d<WD;d++){ float v=Ms[n*65+d]; s+=v*v; }
        mno[n]=sqrtf(s);
      }
      if (wid == 8){
        float v=ifcl[OFF_WK+lane]; float s=wredSum(v*v);
        if (lane==0) scal[S_KNW]=sqrtf(s);
      }
      if (wid >= 10 && wid < 14){
        int r=wid-10; float v=ifcl[OFF_RK+r*WD+lane]; float s=wredSum(v*v);
        if (lane==0) scal[S_KNR+r]=sqrtf(s);
      }
      __syncthreads();
      // G: write content weights
      if (tid < NN){
        float dot=0.f;
        #pragma unroll 8
        for (int d=0;d<WD;d++) dot += ifcl[OFF_WK+d]*Ms[tid*65+d];
        float sim = dot/(scal[S_KNW]*mno[tid]+EPSV);
        wcs[tid]=sim*scal[S_WSTR];
      }
      __syncthreads();
      if (tid < NN){ float mx=wredMax(wcs[tid]); if(lane==0) sc[wid]=mx; }
      __syncthreads();
      if (tid < NN){
        float mx=fmaxf(sc[0],sc[1]);
        float e=expf(wcs[tid]-mx);
        wcs[tid]=e;
        float s=wredSum(e); if(lane==0) sc[2+wid]=s;
      }
      __syncthreads();
      if (tid < NN) wcs[tid]=wcs[tid]/(sc[2]+sc[3]);
      __syncthreads();
      // H: usage + allocation + ww
      if (tid < NN){
        float cw = wws[tid];
        float u  = usg[tid] + (1.0f-usg[tid])*cw;
        float psi=1.0f;
        #pragma unroll
        for (int r=0;r<RR;r++) psi *= 1.0f - scal[S_FG+r]*rws[r*NN+tid];
        float us = u*psi;
        usg[tid]=us;
        u2[tid] = EPSV + (1.0f-EPSV)*us;
      }
      __syncthreads();
      if (tid < NN){
        float ui=u2[tid]; float p=1.0f;
        for (int j=0;j<NN;j++){
          float uj=u2[j];
          bool take = (uj<ui) || (uj==ui && j<tid);
          p *= take ? uj : 1.0f;
        }
        float a = (1.0f-ui)*p;
        float wwn = scal[S_WG]*( scal[S_AG]*a + (1.0f-scal[S_AG])*wcs[tid] );
        wws[tid]=wwn;
        float s=wredSum(wwn); if(lane==0) sc[wid]=s;
      }
      __syncthreads();
      if (tid==0) scal[S_WSUM]=sc[0]+sc[1];
      __syncthreads();
      // I: memory erase/add + link update (old prec)
      #pragma unroll
      for (int i=0;i<8;i++){
        int el=tid+i*1024, n=el>>6, d=el&63;
        float w=wws[n];
        Ms[n*65+d] = Ms[n*65+d]*(1.0f - w*ers[d]) + w*wvs[d];
      }
      #pragma unroll
      for (int i=0;i<16;i++){
        int el=tid+i*1024, li=el>>7, lj=el&127;
        float v = (li==lj) ? 0.0f
                : (1.0f - wws[li] - wws[lj])*Ls[li*129+lj] + wws[li]*prc[lj];
        Ls[li*129+lj]=v;
      }
      __syncthreads();
      if (tid < NN) prc[tid] = (1.0f - scal[S_WSUM])*prc[tid] + wws[tid];
      if (tid >= 128 && tid < 256){
        int n=tid-128; float s=0.f;
        #pragma unroll 8
        for (int d=0;d<WD;d++){ float v=Ms[n*65+d]; s+=v*v; }
        mno[n]=sqrtf(s);
      }
      __syncthreads();
      // L: read content weights
      if (tid < RR*NN){
        int r=tid>>7, n=tid&127;
        float dot=0.f;
        #pragma unroll 8
        for (int d=0;d<WD;d++) dot += ifcl[OFF_RK+r*WD+d]*Ms[n*65+d];
        float sim = dot/(scal[S_KNR+r]*mno[n]+EPSV);
        rcs[tid]=sim*scal[S_RSTR+r];
      }
      __syncthreads();
      if (tid < RR*NN){ float mx=wredMax(rcs[tid]); if(lane==0) sc[wid]=mx; }
      __syncthreads();
      if (tid < RR*NN){
        int r=tid>>7;
        float mx=fmaxf(sc[r*2],sc[r*2+1]);
        float e=expf(rcs[tid]-mx);
        rcs[tid]=e;
        float s=wredSum(e); if(lane==0) sc[8+wid]=s;
      }
      __syncthreads();
      if (tid < RR*NN){
        int r=tid>>7;
        rcs[tid]=rcs[tid]/(sc[8+r*2]+sc[9+r*2]);
      }
      __syncthreads();
      // M: fwd/bwd link matvecs then rw update
      if (tid < RR*NN){
        int r=tid>>7, i=tid&127;
        float f=0.f, bw=0.f;
        const float* rwr = rws + r*NN;
        #pragma unroll 4
        for (int j=0;j<NN;j++){
          float rv=rwr[j];
          f  += Ls[i*129+j]*rv;
          bw += Ls[j*129+i]*rv;
        }
        fwds[tid]=f; bwds[tid]=bw;
      }
      __syncthreads();
      if (tid < RR*NN){
        int r=tid>>7;
        rws[tid] = scal[S_BM+r]*bwds[tid] + scal[S_CM+r]*rcs[tid] + scal[S_FM+r]*fwds[tid];
      }
      __syncthreads();
      // N: reads = rw @ M
      if (tid < RR*WD){
        int r=tid>>6, d=tid&63;
        float s=0.f;
        #pragma unroll 8
        for (int n=0;n<NN;n++) s += rws[r*NN+n]*Ms[n*65+d];
        rds[tid]=s;
      }
      __syncthreads();
      // O: output projection (16-way K split) + export reads
      {
        int kq = tid>>6, c = tid&63;
        const float* xbase = (kq<8) ? (ctll + kq*32) : (rds + (kq-8)*32);
        const float* Wp = Woutg + (kq*32)*OUTW + c;
        float a=0.f;
        #pragma unroll 8
        for (int k=0;k<32;k++) a += xbase[k]*Wp[k*OUTW];
        part[kq*64 + c] = a;
      }
      __syncthreads();
      if (tid < OUTW){
        float a = boutg[tid];
        #pragma unroll
        for (int q=0;q<16;q++) a += part[q*64 + tid];
        outg[(t*BB+b)*OUTW+tid] = fminf(CLIPV, fmaxf(-CLIPV, a));
      } else if (tid >= 64 && tid < 320){
        greads[b*256 + tid-64] = rds[tid-64];
      }
    }
    grid.sync();
  }
}

extern "C" void kernel_launch(void* const* d_in, const int* in_sizes, int n_in,
                              void* d_out, int out_size, void* d_ws, size_t ws_size,
                              hipStream_t stream)
{
  const float* inputs=(const float*)d_in[0];
  const float* Wx0   =(const float*)d_in[1];
  const float* Wh0   =(const float*)d_in[2];
  const float* b0    =(const float*)d_in[3];
  const float* Wx1   =(const float*)d_in[4];
  const float* Wh1   =(const float*)d_in[5];
  const float* b1    =(const float*)d_in[6];
  const float* Wif   =(const float*)d_in[7];
  const float* bif   =(const float*)d_in[8];
  const float* Wout  =(const float*)d_in[9];
  const float* bout  =(const float*)d_in[10];
  float* out = (float*)d_out;
  float* ws  = (float*)d_ws;

  hipFuncSetAttribute((const void*)dnc_coop,
                      hipFuncAttributeMaxDynamicSharedMemorySize, SMEM_BYTES);

  void* args[] = { (void*)&inputs, (void*)&Wx0, (void*)&Wh0, (void*)&b0,
                   (void*)&Wx1, (void*)&Wh1, (void*)&b1, (void*)&Wif,
                   (void*)&bif, (void*)&Wout, (void*)&bout, (void*)&out,
                   (void*)&ws };
  hipLaunchCooperativeKernel((void*)dnc_coop, dim3(BB), dim3(1024),
                             args, SMEM_BYTES, stream);
}